// Round 1
// baseline (597.405 us; speedup 1.0000x reference)
//
#include <hip/hip_runtime.h>

#define N_NODES 100000
#define N_EDGES 3200000

// ---------------------------------------------------------------------------
// Workspace layout (floats):
//   [0,        N)      deg      (zeroed)
//   [N,       2N)      agg2     (zeroed)
//   [2N,     18N)      agg1     (zeroed)   <- deg..agg1 contiguous 18N zero
//   [18N,    34N)      p1  = x @ Wl1^T
//   [34N,    50N)      q1b = x @ Wr1^T + b1
//   [50N,    66N)      h
//   [66N,    67N)      p2  = h @ Wl2^T
//   [67N,    68N)      deg_inv
// ---------------------------------------------------------------------------

__global__ __launch_bounds__(256) void k_proj1(
    const float* __restrict__ x, const float* __restrict__ Wl1,
    const float* __restrict__ Wr1, const float* __restrict__ b1,
    float* __restrict__ p1, float* __restrict__ q1b) {
  __shared__ float sWl[16 * 32];
  __shared__ float sWr[16 * 32];
  __shared__ float sb[16];
  const int t = threadIdx.x;
  for (int i = t; i < 512; i += 256) {
    sWl[i] = Wl1[i];
    sWr[i] = Wr1[i];
  }
  if (t < 16) sb[t] = b1[t];
  __syncthreads();

  const int n = blockIdx.x * 256 + t;
  if (n >= N_NODES) return;

  float xr[32];
  const float4* xp = (const float4*)(x + (size_t)n * 32);
#pragma unroll
  for (int j = 0; j < 8; ++j) {
    float4 v = xp[j];
    xr[4 * j + 0] = v.x;
    xr[4 * j + 1] = v.y;
    xr[4 * j + 2] = v.z;
    xr[4 * j + 3] = v.w;
  }

  float pv[16], qv[16];
#pragma unroll
  for (int hh = 0; hh < 16; ++hh) {
    float a = 0.f, b = 0.f;
#pragma unroll
    for (int i = 0; i < 32; ++i) {
      a = fmaf(xr[i], sWl[hh * 32 + i], a);
      b = fmaf(xr[i], sWr[hh * 32 + i], b);
    }
    pv[hh] = a;
    qv[hh] = b + sb[hh];
  }

  float4* pp = (float4*)(p1 + (size_t)n * 16);
  float4* qp = (float4*)(q1b + (size_t)n * 16);
#pragma unroll
  for (int j = 0; j < 4; ++j) {
    pp[j] = make_float4(pv[4 * j], pv[4 * j + 1], pv[4 * j + 2], pv[4 * j + 3]);
    qp[j] = make_float4(qv[4 * j], qv[4 * j + 1], qv[4 * j + 2], qv[4 * j + 3]);
  }
}

__global__ __launch_bounds__(256) void k_scatter1(
    const int* __restrict__ ei, const float* __restrict__ p1,
    float* __restrict__ agg1, float* __restrict__ deg) {
  const int gid = blockIdx.x * 256 + threadIdx.x;
  if (gid >= 16 * N_EDGES) return;
  const int e = gid >> 4;
  const int c = gid & 15;
  const int s = ei[e];
  const int d = ei[N_EDGES + e];
  atomicAdd(&agg1[(size_t)d * 16 + c], p1[(size_t)s * 16 + c]);
  if (c == 0) atomicAdd(&deg[d], 1.0f);
}

__global__ __launch_bounds__(256) void k_h(
    const float* __restrict__ agg1, const float* __restrict__ q1b,
    const float* __restrict__ deg, const float* __restrict__ Wl2,
    float* __restrict__ h, float* __restrict__ p2,
    float* __restrict__ deg_inv) {
  __shared__ float sW[16];
  if (threadIdx.x < 16) sW[threadIdx.x] = Wl2[threadIdx.x];
  __syncthreads();
  const int n = blockIdx.x * 256 + threadIdx.x;
  if (n >= N_NODES) return;

  const float di = 1.0f / fmaxf(deg[n], 1.0f);
  deg_inv[n] = di;

  const float4* ap = (const float4*)(agg1 + (size_t)n * 16);
  const float4* qp = (const float4*)(q1b + (size_t)n * 16);
  float4* hp = (float4*)(h + (size_t)n * 16);
  float acc = 0.f;
#pragma unroll
  for (int j = 0; j < 4; ++j) {
    float4 a = ap[j];
    float4 q = qp[j];
    float4 hv;
    hv.x = fmaxf(fmaf(a.x, di, q.x), 0.f);
    hv.y = fmaxf(fmaf(a.y, di, q.y), 0.f);
    hv.z = fmaxf(fmaf(a.z, di, q.z), 0.f);
    hv.w = fmaxf(fmaf(a.w, di, q.w), 0.f);
    hp[j] = hv;
    acc = fmaf(hv.x, sW[4 * j + 0], acc);
    acc = fmaf(hv.y, sW[4 * j + 1], acc);
    acc = fmaf(hv.z, sW[4 * j + 2], acc);
    acc = fmaf(hv.w, sW[4 * j + 3], acc);
  }
  p2[n] = acc;
}

__global__ __launch_bounds__(256) void k_scatter2(
    const int* __restrict__ ei, const float* __restrict__ p2,
    float* __restrict__ agg2) {
  const int e = blockIdx.x * 256 + threadIdx.x;
  if (e >= N_EDGES) return;
  const int s = ei[e];
  const int d = ei[N_EDGES + e];
  atomicAdd(&agg2[d], p2[s]);
}

__global__ __launch_bounds__(256) void k_out(
    const float* __restrict__ h, const float* __restrict__ agg2,
    const float* __restrict__ deg_inv, const float* __restrict__ Wr2,
    const float* __restrict__ b2, float* __restrict__ out) {
  __shared__ float sW[16];
  __shared__ float sb2;
  if (threadIdx.x < 16) sW[threadIdx.x] = Wr2[threadIdx.x];
  if (threadIdx.x == 0) sb2 = b2[0];
  __syncthreads();
  const int n = blockIdx.x * 256 + threadIdx.x;
  if (n >= N_NODES) return;

  float acc = fmaf(deg_inv[n], agg2[n], sb2);
  const float4* hp = (const float4*)(h + (size_t)n * 16);
#pragma unroll
  for (int j = 0; j < 4; ++j) {
    float4 hv = hp[j];
    acc = fmaf(hv.x, sW[4 * j + 0], acc);
    acc = fmaf(hv.y, sW[4 * j + 1], acc);
    acc = fmaf(hv.z, sW[4 * j + 2], acc);
    acc = fmaf(hv.w, sW[4 * j + 3], acc);
  }
  out[n] = acc;
}

extern "C" void kernel_launch(void* const* d_in, const int* in_sizes, int n_in,
                              void* d_out, int out_size, void* d_ws,
                              size_t ws_size, hipStream_t stream) {
  const float* x   = (const float*)d_in[0];
  const int*   ei  = (const int*)d_in[1];
  const float* Wl1 = (const float*)d_in[2];
  const float* Wr1 = (const float*)d_in[3];
  const float* b1  = (const float*)d_in[4];
  const float* Wl2 = (const float*)d_in[5];
  const float* Wr2 = (const float*)d_in[6];
  const float* b2  = (const float*)d_in[7];
  float* out = (float*)d_out;

  float* ws = (float*)d_ws;
  const size_t N = N_NODES;
  float* deg     = ws;
  float* agg2    = ws + N;
  float* agg1    = ws + 2 * N;
  float* p1      = ws + 18 * N;
  float* q1b     = ws + 34 * N;
  float* h       = ws + 50 * N;
  float* p2      = ws + 66 * N;
  float* deg_inv = ws + 67 * N;

  // zero deg + agg2 + agg1 (contiguous 18N floats)
  hipMemsetAsync(d_ws, 0, 18 * N * sizeof(float), stream);

  const int nodeBlocks = (N_NODES + 255) / 256;
  k_proj1<<<nodeBlocks, 256, 0, stream>>>(x, Wl1, Wr1, b1, p1, q1b);

  const int sc1Blocks = (16 * N_EDGES + 255) / 256;
  k_scatter1<<<sc1Blocks, 256, 0, stream>>>(ei, p1, agg1, deg);

  k_h<<<nodeBlocks, 256, 0, stream>>>(agg1, q1b, deg, Wl2, h, p2, deg_inv);

  const int sc2Blocks = (N_EDGES + 255) / 256;
  k_scatter2<<<sc2Blocks, 256, 0, stream>>>(ei, p2, agg2);

  k_out<<<nodeBlocks, 256, 0, stream>>>(h, agg2, deg_inv, Wr2, b2, out);
}

// Round 2
// 575.767 us; speedup vs baseline: 1.0376x; 1.0376x over previous
//
#include <hip/hip_runtime.h>

#define N_NODES 100000
#define N_EDGES 3200000
#define SCAN_BS 512
#define SCAN_NB ((N_NODES + SCAN_BS - 1) / SCAN_BS)   // 196

// ---------------------------------------------------------------------------
// Workspace layout (4-byte elements):
//   ints:
//     [0,    N)          cnt        (zeroed; degree histogram)
//     [N,   2N)          offsets    (exclusive scan of cnt)
//     [2N,  3N)          pos        (running fill cursor, init = offsets)
//     [3N,  3N+256)      blocksums
//     [3N+512, 3N+768)   blockoffs
//     [3N+1024, 3N+1024+E)  srcsorted (src node id per dst-sorted edge)
//   floats (base F0 = 3N+1024+E):
//     [F0,      F0+N)    deg_inv
//     [+N,    +17N)      p1  = x @ Wl1^T
//     [+17N,  +33N)      q1b = x @ Wr1^T + b1
//     [+33N,  +49N)      h
//     [+49N,  +50N)      p2  = h @ Wl2^T
// ---------------------------------------------------------------------------

__global__ __launch_bounds__(256) void k_proj1(
    const float* __restrict__ x, const float* __restrict__ Wl1,
    const float* __restrict__ Wr1, const float* __restrict__ b1,
    float* __restrict__ p1, float* __restrict__ q1b) {
  __shared__ float sWl[16 * 32];
  __shared__ float sWr[16 * 32];
  __shared__ float sb[16];
  const int t = threadIdx.x;
  for (int i = t; i < 512; i += 256) {
    sWl[i] = Wl1[i];
    sWr[i] = Wr1[i];
  }
  if (t < 16) sb[t] = b1[t];
  __syncthreads();

  const int n = blockIdx.x * 256 + t;
  if (n >= N_NODES) return;

  float xr[32];
  const float4* xp = (const float4*)(x + (size_t)n * 32);
#pragma unroll
  for (int j = 0; j < 8; ++j) {
    float4 v = xp[j];
    xr[4 * j + 0] = v.x;
    xr[4 * j + 1] = v.y;
    xr[4 * j + 2] = v.z;
    xr[4 * j + 3] = v.w;
  }

  float pv[16], qv[16];
#pragma unroll
  for (int hh = 0; hh < 16; ++hh) {
    float a = 0.f, b = 0.f;
#pragma unroll
    for (int i = 0; i < 32; ++i) {
      a = fmaf(xr[i], sWl[hh * 32 + i], a);
      b = fmaf(xr[i], sWr[hh * 32 + i], b);
    }
    pv[hh] = a;
    qv[hh] = b + sb[hh];
  }

  float4* pp = (float4*)(p1 + (size_t)n * 16);
  float4* qp = (float4*)(q1b + (size_t)n * 16);
#pragma unroll
  for (int j = 0; j < 4; ++j) {
    pp[j] = make_float4(pv[4 * j], pv[4 * j + 1], pv[4 * j + 2], pv[4 * j + 3]);
    qp[j] = make_float4(qv[4 * j], qv[4 * j + 1], qv[4 * j + 2], qv[4 * j + 3]);
  }
}

__global__ __launch_bounds__(256) void k_hist(const int* __restrict__ ei,
                                              int* __restrict__ cnt) {
  const int e = blockIdx.x * 256 + threadIdx.x;
  if (e >= N_EDGES) return;
  atomicAdd(&cnt[ei[N_EDGES + e]], 1);
}

__global__ __launch_bounds__(SCAN_BS) void k_scan_block(
    const int* __restrict__ cnt, int* __restrict__ offsets,
    int* __restrict__ blocksums) {
  __shared__ int sm[SCAN_BS];
  const int t = threadIdx.x;
  const int i = blockIdx.x * SCAN_BS + t;
  int v = (i < N_NODES) ? cnt[i] : 0;
  sm[t] = v;
  __syncthreads();
#pragma unroll
  for (int o = 1; o < SCAN_BS; o <<= 1) {
    int a = (t >= o) ? sm[t - o] : 0;
    __syncthreads();
    sm[t] += a;
    __syncthreads();
  }
  if (i < N_NODES) offsets[i] = sm[t] - v;  // exclusive, block-local
  if (t == SCAN_BS - 1) blocksums[blockIdx.x] = sm[t];
}

__global__ __launch_bounds__(256) void k_scan_top(
    const int* __restrict__ blocksums, int* __restrict__ blockoffs) {
  __shared__ int sm[256];
  const int t = threadIdx.x;
  int v = (t < SCAN_NB) ? blocksums[t] : 0;
  sm[t] = v;
  __syncthreads();
#pragma unroll
  for (int o = 1; o < 256; o <<= 1) {
    int a = (t >= o) ? sm[t - o] : 0;
    __syncthreads();
    sm[t] += a;
    __syncthreads();
  }
  if (t < SCAN_NB) blockoffs[t] = sm[t] - v;  // exclusive
}

__global__ __launch_bounds__(256) void k_scan_add(
    const int* __restrict__ cnt, int* __restrict__ offsets,
    const int* __restrict__ blockoffs, int* __restrict__ pos,
    float* __restrict__ deg_inv) {
  const int i = blockIdx.x * 256 + threadIdx.x;
  if (i >= N_NODES) return;
  const int off = offsets[i] + blockoffs[i / SCAN_BS];
  offsets[i] = off;
  pos[i] = off;
  deg_inv[i] = 1.0f / fmaxf((float)cnt[i], 1.0f);
}

__global__ __launch_bounds__(256) void k_fill(const int* __restrict__ ei,
                                              int* __restrict__ pos,
                                              int* __restrict__ srcsorted) {
  const int e = blockIdx.x * 256 + threadIdx.x;
  if (e >= N_EDGES) return;
  const int s = ei[e];
  const int d = ei[N_EDGES + e];
  const int p = atomicAdd(&pos[d], 1);
  srcsorted[p] = s;
}

// gather layer 1 + relu + h + p2  (16 lanes per node, lane = channel)
__global__ __launch_bounds__(256) void k_agg1h(
    const int* __restrict__ offsets, const int* __restrict__ cnt,
    const int* __restrict__ srcsorted, const float* __restrict__ p1,
    const float* __restrict__ q1b, const float* __restrict__ deg_inv,
    const float* __restrict__ Wl2, float* __restrict__ h,
    float* __restrict__ p2) {
  __shared__ float sW[16];
  if (threadIdx.x < 16) sW[threadIdx.x] = Wl2[threadIdx.x];
  __syncthreads();
  const int n = blockIdx.x * 16 + (threadIdx.x >> 4);
  const int c = threadIdx.x & 15;
  if (n >= N_NODES) return;

  const int off = offsets[n];
  const int k = cnt[n];
  float acc = 0.f;
  int j = 0;
  for (; j + 4 <= k; j += 4) {
    const int s0 = srcsorted[off + j + 0];
    const int s1 = srcsorted[off + j + 1];
    const int s2 = srcsorted[off + j + 2];
    const int s3 = srcsorted[off + j + 3];
    float a0 = p1[(size_t)s0 * 16 + c];
    float a1 = p1[(size_t)s1 * 16 + c];
    float a2 = p1[(size_t)s2 * 16 + c];
    float a3 = p1[(size_t)s3 * 16 + c];
    acc += (a0 + a1) + (a2 + a3);
  }
  for (; j < k; ++j) acc += p1[(size_t)srcsorted[off + j] * 16 + c];

  const float hv =
      fmaxf(fmaf(acc, deg_inv[n], q1b[(size_t)n * 16 + c]), 0.f);
  h[(size_t)n * 16 + c] = hv;

  float pv = hv * sW[c];
#pragma unroll
  for (int m = 8; m >= 1; m >>= 1) pv += __shfl_xor(pv, m, 16);
  if (c == 0) p2[n] = pv;
}

// gather layer 2 + final output  (16 lanes per node)
__global__ __launch_bounds__(256) void k_agg2out(
    const int* __restrict__ offsets, const int* __restrict__ cnt,
    const int* __restrict__ srcsorted, const float* __restrict__ p2,
    const float* __restrict__ h, const float* __restrict__ deg_inv,
    const float* __restrict__ Wr2, const float* __restrict__ b2,
    float* __restrict__ out) {
  __shared__ float sW[16];
  __shared__ float sb2;
  if (threadIdx.x < 16) sW[threadIdx.x] = Wr2[threadIdx.x];
  if (threadIdx.x == 0) sb2 = b2[0];
  __syncthreads();
  const int n = blockIdx.x * 16 + (threadIdx.x >> 4);
  const int c = threadIdx.x & 15;
  if (n >= N_NODES) return;

  const int off = offsets[n];
  const int k = cnt[n];
  float u = 0.f;  // partial sum of p2 over this node's edges
  for (int j = c; j < k; j += 16) u += p2[srcsorted[off + j]];
  float w = h[(size_t)n * 16 + c] * sW[c];  // partial h @ Wr2
#pragma unroll
  for (int m = 8; m >= 1; m >>= 1) {
    u += __shfl_xor(u, m, 16);
    w += __shfl_xor(w, m, 16);
  }
  if (c == 0) out[n] = fmaf(u, deg_inv[n], w + sb2);
}

extern "C" void kernel_launch(void* const* d_in, const int* in_sizes, int n_in,
                              void* d_out, int out_size, void* d_ws,
                              size_t ws_size, hipStream_t stream) {
  const float* x   = (const float*)d_in[0];
  const int*   ei  = (const int*)d_in[1];
  const float* Wl1 = (const float*)d_in[2];
  const float* Wr1 = (const float*)d_in[3];
  const float* b1  = (const float*)d_in[4];
  const float* Wl2 = (const float*)d_in[5];
  const float* Wr2 = (const float*)d_in[6];
  const float* b2  = (const float*)d_in[7];
  float* out = (float*)d_out;

  const size_t N = N_NODES;
  int* wi = (int*)d_ws;
  int* cnt       = wi;
  int* offsets   = wi + N;
  int* pos       = wi + 2 * N;
  int* blocksums = wi + 3 * N;
  int* blockoffs = wi + 3 * N + 512;
  int* srcsorted = wi + 3 * N + 1024;
  float* wf = (float*)(srcsorted + N_EDGES);
  float* deg_inv = wf;
  float* p1      = wf + N;
  float* q1b     = wf + 17 * N;
  float* h       = wf + 33 * N;
  float* p2      = wf + 49 * N;

  hipMemsetAsync(cnt, 0, N * sizeof(int), stream);

  const int nodeBlocks = (N_NODES + 255) / 256;
  const int edgeBlocks = (N_EDGES + 255) / 256;
  const int nodeBlocks16 = (N_NODES + 15) / 16;

  k_proj1<<<nodeBlocks, 256, 0, stream>>>(x, Wl1, Wr1, b1, p1, q1b);
  k_hist<<<edgeBlocks, 256, 0, stream>>>(ei, cnt);
  k_scan_block<<<SCAN_NB, SCAN_BS, 0, stream>>>(cnt, offsets, blocksums);
  k_scan_top<<<1, 256, 0, stream>>>(blocksums, blockoffs);
  k_scan_add<<<nodeBlocks, 256, 0, stream>>>(cnt, offsets, blockoffs, pos,
                                             deg_inv);
  k_fill<<<edgeBlocks, 256, 0, stream>>>(ei, pos, srcsorted);
  k_agg1h<<<nodeBlocks16, 256, 0, stream>>>(offsets, cnt, srcsorted, p1, q1b,
                                            deg_inv, Wl2, h, p2);
  k_agg2out<<<nodeBlocks16, 256, 0, stream>>>(offsets, cnt, srcsorted, p2, h,
                                              deg_inv, Wr2, b2, out);
}

// Round 3
// 549.140 us; speedup vs baseline: 1.0879x; 1.0485x over previous
//
#include <hip/hip_runtime.h>

#define N_NODES 100000
#define N_EDGES 3200000
#define NB_F 782                       // fine buckets: 128 dst nodes each
#define TILE 8192
#define NTILES ((N_EDGES + TILE - 1) / TILE)   // 391
#define EPT (TILE / 256)               // edges per thread per tile = 32

// ---------------------------------------------------------------------------
// Workspace layout (4-byte elements):
//   ints:
//     [0,    1024)        bcnt     (zeroed; per-bucket edge counts)
//     [1024, 2048)        offsets  (exclusive scan, +total at [1024+NB_F])
//     [2048, 3072)        gcur     (running cursors, init = offsets)
//     [3072, 3072+E)      recs     (packed (local_dst<<17)|src, dst-bucketed)
//   floats (F0 = 3072+E):
//     [F0,      +16N)     p1  = x @ Wl1^T
//     [+16N,   +32N)      q1b = x @ Wr1^T + b1
//     [+32N,   +33N)      p2  = h @ Wl2^T
//     [+33N,   +34N)      r2  = h @ Wr2^T
//     [+34N,   +35N)      deg_inv
// ---------------------------------------------------------------------------

__global__ __launch_bounds__(256) void k_proj1(
    const float* __restrict__ x, const float* __restrict__ Wl1,
    const float* __restrict__ Wr1, const float* __restrict__ b1,
    float* __restrict__ p1, float* __restrict__ q1b) {
  __shared__ float sWl[16 * 32];
  __shared__ float sWr[16 * 32];
  __shared__ float sb[16];
  const int t = threadIdx.x;
  for (int i = t; i < 512; i += 256) {
    sWl[i] = Wl1[i];
    sWr[i] = Wr1[i];
  }
  if (t < 16) sb[t] = b1[t];
  __syncthreads();

  const int n = blockIdx.x * 256 + t;
  if (n >= N_NODES) return;

  float xr[32];
  const float4* xp = (const float4*)(x + (size_t)n * 32);
#pragma unroll
  for (int j = 0; j < 8; ++j) {
    float4 v = xp[j];
    xr[4 * j + 0] = v.x;
    xr[4 * j + 1] = v.y;
    xr[4 * j + 2] = v.z;
    xr[4 * j + 3] = v.w;
  }

  float pv[16], qv[16];
#pragma unroll
  for (int hh = 0; hh < 16; ++hh) {
    float a = 0.f, b = 0.f;
#pragma unroll
    for (int i = 0; i < 32; ++i) {
      a = fmaf(xr[i], sWl[hh * 32 + i], a);
      b = fmaf(xr[i], sWr[hh * 32 + i], b);
    }
    pv[hh] = a;
    qv[hh] = b + sb[hh];
  }

  float4* pp = (float4*)(p1 + (size_t)n * 16);
  float4* qp = (float4*)(q1b + (size_t)n * 16);
#pragma unroll
  for (int j = 0; j < 4; ++j) {
    pp[j] = make_float4(pv[4 * j], pv[4 * j + 1], pv[4 * j + 2], pv[4 * j + 3]);
    qp[j] = make_float4(qv[4 * j], qv[4 * j + 1], qv[4 * j + 2], qv[4 * j + 3]);
  }
}

// per-bucket edge counts via LDS pre-aggregation (306K hot-line atomics total)
__global__ __launch_bounds__(256) void k_bhist(const int* __restrict__ dst,
                                               int* __restrict__ bcnt) {
  __shared__ int cnt[NB_F];
  const int t = threadIdx.x;
  for (int i = t; i < NB_F; i += 256) cnt[i] = 0;
  __syncthreads();
  const int tb = blockIdx.x * TILE;
#pragma unroll
  for (int i = 0; i < EPT; ++i) {
    const int e = tb + t + i * 256;
    if (e < N_EDGES) atomicAdd(&cnt[dst[e] >> 7], 1);
  }
  __syncthreads();
  for (int i = t; i < NB_F; i += 256)
    if (cnt[i]) atomicAdd(&bcnt[i], cnt[i]);
}

__global__ __launch_bounds__(1024) void k_bscan(const int* __restrict__ bcnt,
                                                int* __restrict__ offsets,
                                                int* __restrict__ gcur) {
  __shared__ int sm[1024];
  const int t = threadIdx.x;
  const int v = (t < NB_F) ? bcnt[t] : 0;
  sm[t] = v;
  __syncthreads();
#pragma unroll
  for (int o = 1; o < 1024; o <<= 1) {
    const int a = (t >= o) ? sm[t - o] : 0;
    __syncthreads();
    sm[t] += a;
    __syncthreads();
  }
  if (t < NB_F) {
    const int ex = sm[t] - v;
    offsets[t] = ex;
    gcur[t] = ex;
    if (t == NB_F - 1) offsets[NB_F] = sm[t];
  }
}

// bucketed counting-sort scatter: per-(tile,bucket) reserved runs so each
// bucket line is written from ONE block (one XCD L2) -> writebacks merge.
__global__ __launch_bounds__(256) void k_bscatter(const int* __restrict__ ei,
                                                  int* __restrict__ gcur,
                                                  int* __restrict__ recs) {
  __shared__ int cnt[NB_F];
  __shared__ int rbase[NB_F];
  const int t = threadIdx.x;
  for (int i = t; i < NB_F; i += 256) cnt[i] = 0;
  __syncthreads();
  const int tb = blockIdx.x * TILE;
  int ds[EPT];
#pragma unroll
  for (int i = 0; i < EPT; ++i) {
    const int e = tb + t + i * 256;
    ds[i] = (e < N_EDGES) ? ei[N_EDGES + e] : -1;
    if (ds[i] >= 0) atomicAdd(&cnt[ds[i] >> 7], 1);
  }
  __syncthreads();
  for (int i = t; i < NB_F; i += 256) {
    const int c = cnt[i];
    if (c) rbase[i] = atomicAdd(&gcur[i], c);
  }
  __syncthreads();
#pragma unroll
  for (int i = 0; i < EPT; ++i) {
    const int e = tb + t + i * 256;
    if (e < N_EDGES) {
      const int d = ds[i];
      const int s = ei[e];
      const int k = d >> 7;
      const int slot = atomicAdd(&cnt[k], -1) - 1;
      recs[rbase[k] + slot] = ((d & 127) << 17) | s;
    }
  }
}

// layer-1 aggregation per bucket: LDS acc[128][16], then fused
// relu + p2 = h@Wl2^T + r2 = h@Wr2^T + deg_inv. h never materialized.
__global__ __launch_bounds__(256) void k_agg1(
    const int* __restrict__ offsets, const int* __restrict__ recs,
    const float* __restrict__ p1, const float* __restrict__ q1b,
    const float* __restrict__ Wl2, const float* __restrict__ Wr2,
    float* __restrict__ p2, float* __restrict__ r2,
    float* __restrict__ deg_inv) {
  __shared__ float acc[128 * 16];
  __shared__ int cntL[128];
  __shared__ float sWl[16], sWr[16];
  const int t = threadIdx.x;
  for (int i = t; i < 2048; i += 256) acc[i] = 0.f;
  if (t < 128) cntL[t] = 0;
  if (t < 16) {
    sWl[t] = Wl2[t];
    sWr[t] = Wr2[t];
  }
  __syncthreads();
  const int kb = blockIdx.x;
  const int o0 = offsets[kb];
  const int o1 = offsets[kb + 1];
  const int g = t >> 4;
  const int c = t & 15;
  for (int r = o0 + g; r < o1; r += 16) {
    const int rec = recs[r];
    const int s = rec & 0x1FFFF;
    const int local = rec >> 17;
    atomicAdd(&acc[local * 16 + c], p1[(size_t)s * 16 + c]);
    if (c == 0) atomicAdd(&cntL[local], 1);
  }
  __syncthreads();
  const int nb0 = kb * 128;
#pragma unroll
  for (int i = 0; i < 8; ++i) {
    const int local = g + i * 16;
    const int n = nb0 + local;
    if (n < N_NODES) {
      const float di = 1.f / fmaxf((float)cntL[local], 1.f);
      const float hv =
          fmaxf(fmaf(acc[local * 16 + c], di, q1b[(size_t)n * 16 + c]), 0.f);
      float a = hv * sWl[c];
      float b = hv * sWr[c];
#pragma unroll
      for (int m = 8; m >= 1; m >>= 1) {
        a += __shfl_xor(a, m, 16);
        b += __shfl_xor(b, m, 16);
      }
      if (c == 0) {
        p2[n] = a;
        r2[n] = b;
        deg_inv[n] = di;
      }
    }
  }
}

// layer-2 aggregation per bucket + final output
__global__ __launch_bounds__(256) void k_agg2(
    const int* __restrict__ offsets, const int* __restrict__ recs,
    const float* __restrict__ p2, const float* __restrict__ r2,
    const float* __restrict__ deg_inv, const float* __restrict__ b2,
    float* __restrict__ out) {
  __shared__ float u[128];
  const int t = threadIdx.x;
  if (t < 128) u[t] = 0.f;
  __syncthreads();
  const int kb = blockIdx.x;
  const int o0 = offsets[kb];
  const int o1 = offsets[kb + 1];
  for (int r = o0 + t; r < o1; r += 256) {
    const int rec = recs[r];
    atomicAdd(&u[rec >> 17], p2[rec & 0x1FFFF]);
  }
  __syncthreads();
  const int n = kb * 128 + t;
  if (t < 128 && n < N_NODES) out[n] = fmaf(u[t], deg_inv[n], r2[n] + b2[0]);
}

extern "C" void kernel_launch(void* const* d_in, const int* in_sizes, int n_in,
                              void* d_out, int out_size, void* d_ws,
                              size_t ws_size, hipStream_t stream) {
  const float* x   = (const float*)d_in[0];
  const int*   ei  = (const int*)d_in[1];
  const float* Wl1 = (const float*)d_in[2];
  const float* Wr1 = (const float*)d_in[3];
  const float* b1  = (const float*)d_in[4];
  const float* Wl2 = (const float*)d_in[5];
  const float* Wr2 = (const float*)d_in[6];
  const float* b2  = (const float*)d_in[7];
  float* out = (float*)d_out;

  const size_t N = N_NODES;
  int* wi = (int*)d_ws;
  int* bcnt    = wi;
  int* offsets = wi + 1024;
  int* gcur    = wi + 2048;
  int* recs    = wi + 3072;
  float* wf = (float*)(recs + N_EDGES);
  float* p1      = wf;
  float* q1b     = wf + 16 * N;
  float* p2      = wf + 32 * N;
  float* r2      = wf + 33 * N;
  float* deg_inv = wf + 34 * N;

  hipMemsetAsync(bcnt, 0, 1024 * sizeof(int), stream);

  const int nodeBlocks = (N_NODES + 255) / 256;
  k_proj1<<<nodeBlocks, 256, 0, stream>>>(x, Wl1, Wr1, b1, p1, q1b);
  k_bhist<<<NTILES, 256, 0, stream>>>(ei + N_EDGES, bcnt);
  k_bscan<<<1, 1024, 0, stream>>>(bcnt, offsets, gcur);
  k_bscatter<<<NTILES, 256, 0, stream>>>(ei, gcur, recs);
  k_agg1<<<NB_F, 256, 0, stream>>>(offsets, recs, p1, q1b, Wl2, Wr2, p2, r2,
                                   deg_inv);
  k_agg2<<<NB_F, 256, 0, stream>>>(offsets, recs, p2, r2, deg_inv, b2, out);
}

// Round 4
// 488.894 us; speedup vs baseline: 1.2220x; 1.1232x over previous
//
#include <hip/hip_runtime.h>

#define N_NODES 100000
#define N_EDGES 3200000
#define NB_F 782                       // fine buckets: 128 dst nodes each
#define TILE 8192
#define NTILES ((N_EDGES + TILE - 1) / TILE)   // 391
#define EPT (TILE / 256)               // edges per thread per tile = 32
#define SSPLIT 4                       // sub-blocks per bucket (agg kernels)

// ---------------------------------------------------------------------------
// Workspace layout (4-byte elements):
//   ints:
//     [0,    1024)        bcnt     (zeroed; per-bucket edge counts)
//     [1024, 2048)        offsets  (exclusive scan, +total at [1024+NB_F])
//     [2048, 3072)        gcur     (running cursors, init = offsets)
//     [3072, 3072+E)      recs     (packed (local_dst<<17)|src, dst-bucketed)
//   floats (F0 = 3072+E):
//     p1      16N    = x @ Wl1^T
//     q1b     16N    = x @ Wr1^T + b1
//     p2       N     = h @ Wl2^T
//     r2       N     = h @ Wr2^T
//     deg_inv  N
//     pacc    SSPLIT*NB_F*2048   layer-1 partial accumulators
//     u_part  SSPLIT*NB_F*128    layer-2 partial sums
//   ints again:
//     pcnt    SSPLIT*NB_F*128    partial degree counts
// ---------------------------------------------------------------------------

__global__ __launch_bounds__(256) void k_proj1(
    const float* __restrict__ x, const float* __restrict__ Wl1,
    const float* __restrict__ Wr1, const float* __restrict__ b1,
    float* __restrict__ p1, float* __restrict__ q1b) {
  __shared__ float sWl[16 * 32];
  __shared__ float sWr[16 * 32];
  __shared__ float sb[16];
  const int t = threadIdx.x;
  for (int i = t; i < 512; i += 256) {
    sWl[i] = Wl1[i];
    sWr[i] = Wr1[i];
  }
  if (t < 16) sb[t] = b1[t];
  __syncthreads();

  const int n = blockIdx.x * 256 + t;
  if (n >= N_NODES) return;

  float xr[32];
  const float4* xp = (const float4*)(x + (size_t)n * 32);
#pragma unroll
  for (int j = 0; j < 8; ++j) {
    float4 v = xp[j];
    xr[4 * j + 0] = v.x;
    xr[4 * j + 1] = v.y;
    xr[4 * j + 2] = v.z;
    xr[4 * j + 3] = v.w;
  }

  float pv[16], qv[16];
#pragma unroll
  for (int hh = 0; hh < 16; ++hh) {
    float a = 0.f, b = 0.f;
#pragma unroll
    for (int i = 0; i < 32; ++i) {
      a = fmaf(xr[i], sWl[hh * 32 + i], a);
      b = fmaf(xr[i], sWr[hh * 32 + i], b);
    }
    pv[hh] = a;
    qv[hh] = b + sb[hh];
  }

  float4* pp = (float4*)(p1 + (size_t)n * 16);
  float4* qp = (float4*)(q1b + (size_t)n * 16);
#pragma unroll
  for (int j = 0; j < 4; ++j) {
    pp[j] = make_float4(pv[4 * j], pv[4 * j + 1], pv[4 * j + 2], pv[4 * j + 3]);
    qp[j] = make_float4(qv[4 * j], qv[4 * j + 1], qv[4 * j + 2], qv[4 * j + 3]);
  }
}

__global__ __launch_bounds__(256) void k_bhist(const int* __restrict__ dst,
                                               int* __restrict__ bcnt) {
  __shared__ int cnt[NB_F];
  const int t = threadIdx.x;
  for (int i = t; i < NB_F; i += 256) cnt[i] = 0;
  __syncthreads();
  const int tb = blockIdx.x * TILE;
#pragma unroll
  for (int i = 0; i < EPT; ++i) {
    const int e = tb + t + i * 256;
    if (e < N_EDGES) atomicAdd(&cnt[dst[e] >> 7], 1);
  }
  __syncthreads();
  for (int i = t; i < NB_F; i += 256)
    if (cnt[i]) atomicAdd(&bcnt[i], cnt[i]);
}

__global__ __launch_bounds__(1024) void k_bscan(const int* __restrict__ bcnt,
                                                int* __restrict__ offsets,
                                                int* __restrict__ gcur) {
  __shared__ int sm[1024];
  const int t = threadIdx.x;
  const int v = (t < NB_F) ? bcnt[t] : 0;
  sm[t] = v;
  __syncthreads();
#pragma unroll
  for (int o = 1; o < 1024; o <<= 1) {
    const int a = (t >= o) ? sm[t - o] : 0;
    __syncthreads();
    sm[t] += a;
    __syncthreads();
  }
  if (t < NB_F) {
    const int ex = sm[t] - v;
    offsets[t] = ex;
    gcur[t] = ex;
    if (t == NB_F - 1) offsets[NB_F] = sm[t];
  }
}

__global__ __launch_bounds__(256) void k_bscatter(const int* __restrict__ ei,
                                                  int* __restrict__ gcur,
                                                  int* __restrict__ recs) {
  __shared__ int cnt[NB_F];
  __shared__ int rbase[NB_F];
  const int t = threadIdx.x;
  for (int i = t; i < NB_F; i += 256) cnt[i] = 0;
  __syncthreads();
  const int tb = blockIdx.x * TILE;
  int ds[EPT];
#pragma unroll
  for (int i = 0; i < EPT; ++i) {
    const int e = tb + t + i * 256;
    ds[i] = (e < N_EDGES) ? ei[N_EDGES + e] : -1;
    if (ds[i] >= 0) atomicAdd(&cnt[ds[i] >> 7], 1);
  }
  __syncthreads();
  for (int i = t; i < NB_F; i += 256) {
    const int c = cnt[i];
    if (c) rbase[i] = atomicAdd(&gcur[i], c);
  }
  __syncthreads();
#pragma unroll
  for (int i = 0; i < EPT; ++i) {
    const int e = tb + t + i * 256;
    if (e < N_EDGES) {
      const int d = ds[i];
      const int s = ei[e];
      const int k = d >> 7;
      const int slot = atomicAdd(&cnt[k], -1) - 1;
      recs[rbase[k] + slot] = ((d & 127) << 17) | s;
    }
  }
}

// layer-1 aggregation: SSPLIT sub-blocks per bucket, 4x-unrolled independent
// gathers for MLP; flush private LDS acc to contiguous partials (no atomics).
__global__ __launch_bounds__(256) void k_agg1(
    const int* __restrict__ offsets, const int* __restrict__ recs,
    const float* __restrict__ p1, float* __restrict__ pacc,
    int* __restrict__ pcnt) {
  __shared__ float acc[2048];
  __shared__ int cntL[128];
  const int t = threadIdx.x;
  for (int i = t; i < 2048; i += 256) acc[i] = 0.f;
  if (t < 128) cntL[t] = 0;
  __syncthreads();

  const int kb = blockIdx.x >> 2;
  const int s = blockIdx.x & 3;
  const int o0 = offsets[kb];
  const int len = offsets[kb + 1] - o0;
  const int cb = o0 + (len * s) / SSPLIT;
  const int ce = o0 + (len * (s + 1)) / SSPLIT;
  const int g = t >> 4;
  const int c = t & 15;

  int r = cb + g;
  for (; r + 48 < ce; r += 64) {
    const int rec0 = recs[r];
    const int rec1 = recs[r + 16];
    const int rec2 = recs[r + 32];
    const int rec3 = recs[r + 48];
    const float v0 = p1[(size_t)(rec0 & 0x1FFFF) * 16 + c];
    const float v1 = p1[(size_t)(rec1 & 0x1FFFF) * 16 + c];
    const float v2 = p1[(size_t)(rec2 & 0x1FFFF) * 16 + c];
    const float v3 = p1[(size_t)(rec3 & 0x1FFFF) * 16 + c];
    atomicAdd(&acc[(rec0 >> 17) * 16 + c], v0);
    atomicAdd(&acc[(rec1 >> 17) * 16 + c], v1);
    atomicAdd(&acc[(rec2 >> 17) * 16 + c], v2);
    atomicAdd(&acc[(rec3 >> 17) * 16 + c], v3);
    if (c == 0) {
      atomicAdd(&cntL[rec0 >> 17], 1);
      atomicAdd(&cntL[rec1 >> 17], 1);
      atomicAdd(&cntL[rec2 >> 17], 1);
      atomicAdd(&cntL[rec3 >> 17], 1);
    }
  }
  for (; r < ce; r += 16) {
    const int rec = recs[r];
    atomicAdd(&acc[(rec >> 17) * 16 + c], p1[(size_t)(rec & 0x1FFFF) * 16 + c]);
    if (c == 0) atomicAdd(&cntL[rec >> 17], 1);
  }
  __syncthreads();

  float* dst = pacc + ((size_t)(s * NB_F + kb) << 11);
  for (int i = t; i < 2048; i += 256) dst[i] = acc[i];
  if (t < 128) pcnt[((size_t)(s * NB_F + kb) << 7) + t] = cntL[t];
}

// finalize layer 1: sum partials, relu, fused p2/r2/deg_inv (h never stored)
__global__ __launch_bounds__(256) void k_fin1(
    const float* __restrict__ pacc, const int* __restrict__ pcnt,
    const float* __restrict__ q1b, const float* __restrict__ Wl2,
    const float* __restrict__ Wr2, float* __restrict__ p2,
    float* __restrict__ r2, float* __restrict__ deg_inv) {
  __shared__ float sWl[16], sWr[16];
  const int t = threadIdx.x;
  if (t < 16) {
    sWl[t] = Wl2[t];
    sWr[t] = Wr2[t];
  }
  __syncthreads();
  const int n = blockIdx.x * 16 + (t >> 4);
  const int c = t & 15;
  if (n >= N_NODES) return;
  const int kb = n >> 7;
  const int local = n & 127;

  float acc = 0.f;
  int cnt = 0;
#pragma unroll
  for (int s = 0; s < SSPLIT; ++s) {
    acc += pacc[(((size_t)(s * NB_F + kb)) << 11) + local * 16 + c];
    cnt += pcnt[(((size_t)(s * NB_F + kb)) << 7) + local];
  }
  const float di = 1.f / fmaxf((float)cnt, 1.f);
  const float hv = fmaxf(fmaf(acc, di, q1b[(size_t)n * 16 + c]), 0.f);
  float a = hv * sWl[c];
  float b = hv * sWr[c];
#pragma unroll
  for (int m = 8; m >= 1; m >>= 1) {
    a += __shfl_xor(a, m, 16);
    b += __shfl_xor(b, m, 16);
  }
  if (c == 0) {
    p2[n] = a;
    r2[n] = b;
    deg_inv[n] = di;
  }
}

// layer-2 aggregation: SSPLIT sub-blocks per bucket, scalar p2 gathers
__global__ __launch_bounds__(256) void k_agg2(
    const int* __restrict__ offsets, const int* __restrict__ recs,
    const float* __restrict__ p2, float* __restrict__ u_part) {
  __shared__ float u[128];
  const int t = threadIdx.x;
  if (t < 128) u[t] = 0.f;
  __syncthreads();
  const int kb = blockIdx.x >> 2;
  const int s = blockIdx.x & 3;
  const int o0 = offsets[kb];
  const int len = offsets[kb + 1] - o0;
  const int cb = o0 + (len * s) / SSPLIT;
  const int ce = o0 + (len * (s + 1)) / SSPLIT;

  int r = cb + t;
  for (; r + 768 < ce; r += 1024) {
    const int rec0 = recs[r];
    const int rec1 = recs[r + 256];
    const int rec2 = recs[r + 512];
    const int rec3 = recs[r + 768];
    const float v0 = p2[rec0 & 0x1FFFF];
    const float v1 = p2[rec1 & 0x1FFFF];
    const float v2 = p2[rec2 & 0x1FFFF];
    const float v3 = p2[rec3 & 0x1FFFF];
    atomicAdd(&u[rec0 >> 17], v0);
    atomicAdd(&u[rec1 >> 17], v1);
    atomicAdd(&u[rec2 >> 17], v2);
    atomicAdd(&u[rec3 >> 17], v3);
  }
  for (; r < ce; r += 256) {
    const int rec = recs[r];
    atomicAdd(&u[rec >> 17], p2[rec & 0x1FFFF]);
  }
  __syncthreads();
  if (t < 128) u_part[(size_t)(s * NB_F + kb) * 128 + t] = u[t];
}

__global__ __launch_bounds__(256) void k_out(
    const float* __restrict__ u_part, const float* __restrict__ r2,
    const float* __restrict__ deg_inv, const float* __restrict__ b2,
    float* __restrict__ out) {
  const int n = blockIdx.x * 256 + threadIdx.x;
  if (n >= N_NODES) return;
  float u = 0.f;
#pragma unroll
  for (int s = 0; s < SSPLIT; ++s) u += u_part[(size_t)s * NB_F * 128 + n];
  out[n] = fmaf(u, deg_inv[n], r2[n] + b2[0]);
}

extern "C" void kernel_launch(void* const* d_in, const int* in_sizes, int n_in,
                              void* d_out, int out_size, void* d_ws,
                              size_t ws_size, hipStream_t stream) {
  const float* x   = (const float*)d_in[0];
  const int*   ei  = (const int*)d_in[1];
  const float* Wl1 = (const float*)d_in[2];
  const float* Wr1 = (const float*)d_in[3];
  const float* b1  = (const float*)d_in[4];
  const float* Wl2 = (const float*)d_in[5];
  const float* Wr2 = (const float*)d_in[6];
  const float* b2  = (const float*)d_in[7];
  float* out = (float*)d_out;

  const size_t N = N_NODES;
  int* wi = (int*)d_ws;
  int* bcnt    = wi;
  int* offsets = wi + 1024;
  int* gcur    = wi + 2048;
  int* recs    = wi + 3072;
  float* wf = (float*)(recs + N_EDGES);
  float* p1      = wf;
  float* q1b     = wf + 16 * N;
  float* p2      = wf + 32 * N;
  float* r2      = wf + 33 * N;
  float* deg_inv = wf + 34 * N;
  float* pacc    = wf + 35 * N;
  float* u_part  = pacc + (size_t)SSPLIT * NB_F * 2048;
  int* pcnt      = (int*)(u_part + (size_t)SSPLIT * NB_F * 128);

  hipMemsetAsync(bcnt, 0, 1024 * sizeof(int), stream);

  const int nodeBlocks = (N_NODES + 255) / 256;
  k_proj1<<<nodeBlocks, 256, 0, stream>>>(x, Wl1, Wr1, b1, p1, q1b);
  k_bhist<<<NTILES, 256, 0, stream>>>(ei + N_EDGES, bcnt);
  k_bscan<<<1, 1024, 0, stream>>>(bcnt, offsets, gcur);
  k_bscatter<<<NTILES, 256, 0, stream>>>(ei, gcur, recs);
  k_agg1<<<NB_F * SSPLIT, 256, 0, stream>>>(offsets, recs, p1, pacc, pcnt);
  k_fin1<<<(N_NODES + 15) / 16, 256, 0, stream>>>(pacc, pcnt, q1b, Wl2, Wr2,
                                                  p2, r2, deg_inv);
  k_agg2<<<NB_F * SSPLIT, 256, 0, stream>>>(offsets, recs, p2, u_part);
  k_out<<<nodeBlocks, 256, 0, stream>>>(u_part, r2, deg_inv, b2, out);
}

// Round 5
// 468.432 us; speedup vs baseline: 1.2753x; 1.0437x over previous
//
#include <hip/hip_runtime.h>

#define N_NODES 100000
#define N_EDGES 3200000
#define NB_F 782                       // fine buckets: 128 dst nodes each
#define TILE 8192
#define NTILES ((N_EDGES + TILE - 1) / TILE)   // 391
#define EPT (TILE / 256)               // edges per thread per tile = 32
#define SSPLIT 4                       // sub-blocks per bucket (agg kernels)

// ---------------------------------------------------------------------------
// Workspace layout (4-byte elements):
//   ints:
//     [0,    1024)        bcnt     (zeroed; per-bucket edge counts)
//     [1024, 2048)        offsets  (exclusive scan, +total at [1024+NB_F])
//     [2048, 3072)        gcur     (running cursors, init = offsets)
//     [3072, 3072+E)      recs     (packed (local_dst<<17)|src, dst-bucketed)
//   then:
//     p1h     16N ushorts (8N words)  = bf16(x @ Wl1^T)  -- 3.2 MB, L2-resident
//     q1b     16N floats              = x @ Wr1^T + b1
//     p2       N  floats   r2  N  floats   deg_inv N floats
//     pacc    SSPLIT*NB_F*2048 floats (layer-1 partial accumulators)
//     u_part  SSPLIT*NB_F*128  floats (layer-2 partial sums)
//     pcnt    SSPLIT*NB_F*128  ints   (partial degree counts)
// ---------------------------------------------------------------------------

__device__ __forceinline__ float bf2f(unsigned short h) {
  return __uint_as_float(((unsigned int)h) << 16);
}
__device__ __forceinline__ unsigned short f2bf(float f) {
  unsigned int b = __float_as_uint(f);
  return (unsigned short)((b + 0x7FFFu + ((b >> 16) & 1u)) >> 16);
}

__global__ __launch_bounds__(256) void k_proj1(
    const float* __restrict__ x, const float* __restrict__ Wl1,
    const float* __restrict__ Wr1, const float* __restrict__ b1,
    unsigned short* __restrict__ p1h, float* __restrict__ q1b) {
  __shared__ float sWl[16 * 32];
  __shared__ float sWr[16 * 32];
  __shared__ float sb[16];
  const int t = threadIdx.x;
  for (int i = t; i < 512; i += 256) {
    sWl[i] = Wl1[i];
    sWr[i] = Wr1[i];
  }
  if (t < 16) sb[t] = b1[t];
  __syncthreads();

  const int n = blockIdx.x * 256 + t;
  if (n >= N_NODES) return;

  float xr[32];
  const float4* xp = (const float4*)(x + (size_t)n * 32);
#pragma unroll
  for (int j = 0; j < 8; ++j) {
    float4 v = xp[j];
    xr[4 * j + 0] = v.x;
    xr[4 * j + 1] = v.y;
    xr[4 * j + 2] = v.z;
    xr[4 * j + 3] = v.w;
  }

  float pv[16], qv[16];
#pragma unroll
  for (int hh = 0; hh < 16; ++hh) {
    float a = 0.f, b = 0.f;
#pragma unroll
    for (int i = 0; i < 32; ++i) {
      a = fmaf(xr[i], sWl[hh * 32 + i], a);
      b = fmaf(xr[i], sWr[hh * 32 + i], b);
    }
    pv[hh] = a;
    qv[hh] = b + sb[hh];
  }

  unsigned int w[8];
#pragma unroll
  for (int j = 0; j < 8; ++j)
    w[j] = (unsigned int)f2bf(pv[2 * j]) |
           ((unsigned int)f2bf(pv[2 * j + 1]) << 16);
  uint4* pp = (uint4*)(p1h + (size_t)n * 16);
  pp[0] = make_uint4(w[0], w[1], w[2], w[3]);
  pp[1] = make_uint4(w[4], w[5], w[6], w[7]);

  float4* qp = (float4*)(q1b + (size_t)n * 16);
#pragma unroll
  for (int j = 0; j < 4; ++j)
    qp[j] = make_float4(qv[4 * j], qv[4 * j + 1], qv[4 * j + 2], qv[4 * j + 3]);
}

__global__ __launch_bounds__(256) void k_bhist(const int* __restrict__ dst,
                                               int* __restrict__ bcnt) {
  __shared__ int cnt[NB_F];
  const int t = threadIdx.x;
  for (int i = t; i < NB_F; i += 256) cnt[i] = 0;
  __syncthreads();
  const int tb = blockIdx.x * TILE;
#pragma unroll
  for (int i = 0; i < EPT; ++i) {
    const int e = tb + t + i * 256;
    if (e < N_EDGES) atomicAdd(&cnt[dst[e] >> 7], 1);
  }
  __syncthreads();
  for (int i = t; i < NB_F; i += 256)
    if (cnt[i]) atomicAdd(&bcnt[i], cnt[i]);
}

__global__ __launch_bounds__(1024) void k_bscan(const int* __restrict__ bcnt,
                                                int* __restrict__ offsets,
                                                int* __restrict__ gcur) {
  __shared__ int sm[1024];
  const int t = threadIdx.x;
  const int v = (t < NB_F) ? bcnt[t] : 0;
  sm[t] = v;
  __syncthreads();
#pragma unroll
  for (int o = 1; o < 1024; o <<= 1) {
    const int a = (t >= o) ? sm[t - o] : 0;
    __syncthreads();
    sm[t] += a;
    __syncthreads();
  }
  if (t < NB_F) {
    const int ex = sm[t] - v;
    offsets[t] = ex;
    gcur[t] = ex;
    if (t == NB_F - 1) offsets[NB_F] = sm[t];
  }
}

__global__ __launch_bounds__(256) void k_bscatter(const int* __restrict__ ei,
                                                  int* __restrict__ gcur,
                                                  int* __restrict__ recs) {
  __shared__ int cnt[NB_F];
  __shared__ int rbase[NB_F];
  const int t = threadIdx.x;
  for (int i = t; i < NB_F; i += 256) cnt[i] = 0;
  __syncthreads();
  const int tb = blockIdx.x * TILE;
  int ds[EPT];
#pragma unroll
  for (int i = 0; i < EPT; ++i) {
    const int e = tb + t + i * 256;
    ds[i] = (e < N_EDGES) ? ei[N_EDGES + e] : -1;
    if (ds[i] >= 0) atomicAdd(&cnt[ds[i] >> 7], 1);
  }
  __syncthreads();
  for (int i = t; i < NB_F; i += 256) {
    const int c = cnt[i];
    if (c) rbase[i] = atomicAdd(&gcur[i], c);
  }
  __syncthreads();
#pragma unroll
  for (int i = 0; i < EPT; ++i) {
    const int e = tb + t + i * 256;
    if (e < N_EDGES) {
      const int d = ds[i];
      const int s = ei[e];
      const int k = d >> 7;
      const int slot = atomicAdd(&cnt[k], -1) - 1;
      recs[rbase[k] + slot] = ((d & 127) << 17) | s;
    }
  }
}

// layer-1 aggregation: bf16 p1 gathers (L2-resident 3.2 MB), LDS accumulate,
// contiguous partial flush (no global atomics).
__global__ __launch_bounds__(256) void k_agg1(
    const int* __restrict__ offsets, const int* __restrict__ recs,
    const unsigned short* __restrict__ p1h, float* __restrict__ pacc,
    int* __restrict__ pcnt) {
  __shared__ float acc[2048];
  __shared__ int cntL[128];
  const int t = threadIdx.x;
  for (int i = t; i < 2048; i += 256) acc[i] = 0.f;
  if (t < 128) cntL[t] = 0;
  __syncthreads();

  const int kb = blockIdx.x >> 2;
  const int s = blockIdx.x & 3;
  const int o0 = offsets[kb];
  const int len = offsets[kb + 1] - o0;
  const int cb = o0 + (len * s) / SSPLIT;
  const int ce = o0 + (len * (s + 1)) / SSPLIT;
  const int g = t >> 4;
  const int c = t & 15;

  int r = cb + g;
  for (; r + 48 < ce; r += 64) {
    const int rec0 = recs[r];
    const int rec1 = recs[r + 16];
    const int rec2 = recs[r + 32];
    const int rec3 = recs[r + 48];
    const float v0 = bf2f(p1h[(size_t)(rec0 & 0x1FFFF) * 16 + c]);
    const float v1 = bf2f(p1h[(size_t)(rec1 & 0x1FFFF) * 16 + c]);
    const float v2 = bf2f(p1h[(size_t)(rec2 & 0x1FFFF) * 16 + c]);
    const float v3 = bf2f(p1h[(size_t)(rec3 & 0x1FFFF) * 16 + c]);
    atomicAdd(&acc[(rec0 >> 17) * 16 + c], v0);
    atomicAdd(&acc[(rec1 >> 17) * 16 + c], v1);
    atomicAdd(&acc[(rec2 >> 17) * 16 + c], v2);
    atomicAdd(&acc[(rec3 >> 17) * 16 + c], v3);
    if (c == 0) {
      atomicAdd(&cntL[rec0 >> 17], 1);
      atomicAdd(&cntL[rec1 >> 17], 1);
      atomicAdd(&cntL[rec2 >> 17], 1);
      atomicAdd(&cntL[rec3 >> 17], 1);
    }
  }
  for (; r < ce; r += 16) {
    const int rec = recs[r];
    atomicAdd(&acc[(rec >> 17) * 16 + c],
              bf2f(p1h[(size_t)(rec & 0x1FFFF) * 16 + c]));
    if (c == 0) atomicAdd(&cntL[rec >> 17], 1);
  }
  __syncthreads();

  float* dst = pacc + ((size_t)(s * NB_F + kb) << 11);
  for (int i = t; i < 2048; i += 256) dst[i] = acc[i];
  if (t < 128) pcnt[((size_t)(s * NB_F + kb) << 7) + t] = cntL[t];
}

// finalize layer 1: sum partials, relu, fused p2/r2/deg_inv (h never stored)
__global__ __launch_bounds__(256) void k_fin1(
    const float* __restrict__ pacc, const int* __restrict__ pcnt,
    const float* __restrict__ q1b, const float* __restrict__ Wl2,
    const float* __restrict__ Wr2, float* __restrict__ p2,
    float* __restrict__ r2, float* __restrict__ deg_inv) {
  __shared__ float sWl[16], sWr[16];
  const int t = threadIdx.x;
  if (t < 16) {
    sWl[t] = Wl2[t];
    sWr[t] = Wr2[t];
  }
  __syncthreads();
  const int n = blockIdx.x * 16 + (t >> 4);
  const int c = t & 15;
  if (n >= N_NODES) return;
  const int kb = n >> 7;
  const int local = n & 127;

  float acc = 0.f;
  int cnt = 0;
#pragma unroll
  for (int s = 0; s < SSPLIT; ++s) {
    acc += pacc[(((size_t)(s * NB_F + kb)) << 11) + local * 16 + c];
    cnt += pcnt[(((size_t)(s * NB_F + kb)) << 7) + local];
  }
  const float di = 1.f / fmaxf((float)cnt, 1.f);
  const float hv = fmaxf(fmaf(acc, di, q1b[(size_t)n * 16 + c]), 0.f);
  float a = hv * sWl[c];
  float b = hv * sWr[c];
#pragma unroll
  for (int m = 8; m >= 1; m >>= 1) {
    a += __shfl_xor(a, m, 16);
    b += __shfl_xor(b, m, 16);
  }
  if (c == 0) {
    p2[n] = a;
    r2[n] = b;
    deg_inv[n] = di;
  }
}

// layer-2 aggregation: p2 (400 KB) is L2-resident fp32
__global__ __launch_bounds__(256) void k_agg2(
    const int* __restrict__ offsets, const int* __restrict__ recs,
    const float* __restrict__ p2, float* __restrict__ u_part) {
  __shared__ float u[128];
  const int t = threadIdx.x;
  if (t < 128) u[t] = 0.f;
  __syncthreads();
  const int kb = blockIdx.x >> 2;
  const int s = blockIdx.x & 3;
  const int o0 = offsets[kb];
  const int len = offsets[kb + 1] - o0;
  const int cb = o0 + (len * s) / SSPLIT;
  const int ce = o0 + (len * (s + 1)) / SSPLIT;

  int r = cb + t;
  for (; r + 768 < ce; r += 1024) {
    const int rec0 = recs[r];
    const int rec1 = recs[r + 256];
    const int rec2 = recs[r + 512];
    const int rec3 = recs[r + 768];
    const float v0 = p2[rec0 & 0x1FFFF];
    const float v1 = p2[rec1 & 0x1FFFF];
    const float v2 = p2[rec2 & 0x1FFFF];
    const float v3 = p2[rec3 & 0x1FFFF];
    atomicAdd(&u[rec0 >> 17], v0);
    atomicAdd(&u[rec1 >> 17], v1);
    atomicAdd(&u[rec2 >> 17], v2);
    atomicAdd(&u[rec3 >> 17], v3);
  }
  for (; r < ce; r += 256) {
    const int rec = recs[r];
    atomicAdd(&u[rec >> 17], p2[rec & 0x1FFFF]);
  }
  __syncthreads();
  if (t < 128) u_part[(size_t)(s * NB_F + kb) * 128 + t] = u[t];
}

__global__ __launch_bounds__(256) void k_out(
    const float* __restrict__ u_part, const float* __restrict__ r2,
    const float* __restrict__ deg_inv, const float* __restrict__ b2,
    float* __restrict__ out) {
  const int n = blockIdx.x * 256 + threadIdx.x;
  if (n >= N_NODES) return;
  float u = 0.f;
#pragma unroll
  for (int s = 0; s < SSPLIT; ++s) u += u_part[(size_t)s * NB_F * 128 + n];
  out[n] = fmaf(u, deg_inv[n], r2[n] + b2[0]);
}

extern "C" void kernel_launch(void* const* d_in, const int* in_sizes, int n_in,
                              void* d_out, int out_size, void* d_ws,
                              size_t ws_size, hipStream_t stream) {
  const float* x   = (const float*)d_in[0];
  const int*   ei  = (const int*)d_in[1];
  const float* Wl1 = (const float*)d_in[2];
  const float* Wr1 = (const float*)d_in[3];
  const float* b1  = (const float*)d_in[4];
  const float* Wl2 = (const float*)d_in[5];
  const float* Wr2 = (const float*)d_in[6];
  const float* b2  = (const float*)d_in[7];
  float* out = (float*)d_out;

  const size_t N = N_NODES;
  int* wi = (int*)d_ws;
  int* bcnt    = wi;
  int* offsets = wi + 1024;
  int* gcur    = wi + 2048;
  int* recs    = wi + 3072;
  unsigned short* p1h = (unsigned short*)(recs + N_EDGES);
  float* q1b     = (float*)(p1h + 16 * N);   // 16N ushorts = 8N words
  float* p2      = q1b + 16 * N;
  float* r2      = p2 + N;
  float* deg_inv = r2 + N;
  float* pacc    = deg_inv + N;
  float* u_part  = pacc + (size_t)SSPLIT * NB_F * 2048;
  int* pcnt      = (int*)(u_part + (size_t)SSPLIT * NB_F * 128);

  hipMemsetAsync(bcnt, 0, 1024 * sizeof(int), stream);

  const int nodeBlocks = (N_NODES + 255) / 256;
  k_proj1<<<nodeBlocks, 256, 0, stream>>>(x, Wl1, Wr1, b1, p1h, q1b);
  k_bhist<<<NTILES, 256, 0, stream>>>(ei + N_EDGES, bcnt);
  k_bscan<<<1, 1024, 0, stream>>>(bcnt, offsets, gcur);
  k_bscatter<<<NTILES, 256, 0, stream>>>(ei, gcur, recs);
  k_agg1<<<NB_F * SSPLIT, 256, 0, stream>>>(offsets, recs, p1h, pacc, pcnt);
  k_fin1<<<(N_NODES + 15) / 16, 256, 0, stream>>>(pacc, pcnt, q1b, Wl2, Wr2,
                                                  p2, r2, deg_inv);
  k_agg2<<<NB_F * SSPLIT, 256, 0, stream>>>(offsets, recs, p2, u_part);
  k_out<<<nodeBlocks, 256, 0, stream>>>(u_part, r2, deg_inv, b2, out);
}